// Round 1
// baseline (636.244 us; speedup 1.0000x reference)
//
#include <hip/hip_runtime.h>

#define B_    8
#define N_    8192
#define S_    2048
#define D1_   128
#define D2_   256
#define CIN_  384
#define CMID_ 256
#define COUT_ 256

// ---------------------------------------------------------------------------
// K1: 3-NN search. Distances in fp64 with the reference formula
// (-2*dot + |p1|^2 + |p2|^2) so near-ties resolve like a float64 numpy ref.
// Strict '<' insertion => ties keep the lower index (top_k stability).
// ---------------------------------------------------------------------------
__global__ __launch_bounds__(256) void k_nn(const float* __restrict__ xyz1,
                                            const float* __restrict__ xyz2,
                                            int4* __restrict__ idx4,
                                            float4* __restrict__ w4) {
  __shared__ float4 sxyz[S_];   // x,y,z (exact fp32 inputs), .w unused
  __shared__ double sqn[S_];    // |p2|^2 in fp64
  const int b = blockIdx.y;
  const float* xb = xyz2 + (size_t)b * 3 * S_;
  for (int s = threadIdx.x; s < S_; s += 256) {
    float x = xb[s], y = xb[S_ + s], z = xb[2 * S_ + s];
    sxyz[s] = make_float4(x, y, z, 0.f);
    sqn[s] = (double)x * x + (double)y * y + (double)z * z;
  }
  __syncthreads();

  const int n = blockIdx.x * 256 + threadIdx.x;
  const float* pb = xyz1 + (size_t)b * 3 * N_;
  const double px = (double)pb[n], py = (double)pb[N_ + n], pz = (double)pb[2 * N_ + n];
  const double pn = px * px + py * py + pz * pz;

  double d0 = 1e300, d1 = 1e300, d2 = 1e300;
  int i0 = 0, i1 = 0, i2 = 0;
#pragma unroll 2
  for (int s = 0; s < S_; ++s) {
    float4 q = sxyz[s];
    double dot = px * (double)q.x + py * (double)q.y + pz * (double)q.z;
    double d = -2.0 * dot + (pn + sqn[s]);
    if (d < d2) {
      if (d < d1) {
        d2 = d1; i2 = i1;
        if (d < d0) { d1 = d0; i1 = i0; d0 = d; i0 = s; }
        else        { d1 = d;  i1 = s; }
      } else { d2 = d; i2 = s; }
    }
  }
  // weights in fp32 like the reference
  float f0 = (float)d0, f1 = (float)d1, f2 = (float)d2;
  float r0 = 1.0f / (f0 + 1e-8f);
  float r1 = 1.0f / (f1 + 1e-8f);
  float r2 = 1.0f / (f2 + 1e-8f);
  float rs = r0 + r1 + r2;
  w4[(size_t)b * N_ + n]   = make_float4(r0 / rs, r1 / rs, r2 / rs, 0.f);
  idx4[(size_t)b * N_ + n] = make_int4(i0, i1, i2, 0);
}

// ---------------------------------------------------------------------------
// K2: gather+interp. Block = (b, 4 channels of points2); stages the 4 channel
// rows (8KB each) in LDS, gathers per-n with coalesced idx/w reads and
// coalesced writes to interp[b][d][n].
// ---------------------------------------------------------------------------
__global__ __launch_bounds__(256) void k_interp(const float* __restrict__ p2,
                                                const int4* __restrict__ idx4,
                                                const float4* __restrict__ w4,
                                                float* __restrict__ interp) {
  __shared__ float rows[4][S_];
  const int b = blockIdx.y;
  const int d0 = blockIdx.x * 4;
  const float* src = p2 + ((size_t)b * D2_ + d0) * S_;
  for (int i = threadIdx.x; i < 4 * S_ / 4; i += 256)
    ((float4*)rows)[i] = ((const float4*)src)[i];
  __syncthreads();

  for (int nc = 0; nc < N_; nc += 256) {
    int n = nc + threadIdx.x;
    int4 id = idx4[(size_t)b * N_ + n];
    float4 w = w4[(size_t)b * N_ + n];
#pragma unroll
    for (int d = 0; d < 4; ++d) {
      float v = rows[d][id.x] * w.x + rows[d][id.y] * w.y + rows[d][id.z] * w.z;
      interp[((size_t)b * D2_ + d0 + d) * N_ + n] = v;
    }
  }
}

// ---------------------------------------------------------------------------
// GEMM1: y1[b,o,n] = sum_c w1[o,c]*x[b,c,n] + b1[o]
//   x rows 0..127 from points1, 128..383 from interp.  BM=BN=128, BK=16,
//   256 thr, 8x8 per thread (two 4-wide groups to stay bank-conflict-free).
// ---------------------------------------------------------------------------
__global__ __launch_bounds__(256) void k_gemm1(const float* __restrict__ W,
                                               const float* __restrict__ bias,
                                               const float* __restrict__ p1,
                                               const float* __restrict__ interp,
                                               float* __restrict__ y1) {
  __shared__ float As[16][132];
  __shared__ float Bs[16][128];
  const int b = blockIdx.z;
  const int bm0 = blockIdx.y * 128;
  const int bn0 = blockIdx.x * 128;
  const int tid = threadIdx.x;
  const int tx = tid & 15, ty = tid >> 4;

  float acc[8][8];
  for (int i = 0; i < 8; ++i)
    for (int j = 0; j < 8; ++j) acc[i][j] = 0.f;

  for (int k0 = 0; k0 < CIN_; k0 += 16) {
    __syncthreads();
#pragma unroll
    for (int i = 0; i < 2; ++i) {
      int li = tid + i * 256;
      int row = li >> 2, qc = li & 3;
      float4 v = *(const float4*)(W + (size_t)(bm0 + row) * CIN_ + k0 + qc * 4);
      As[qc * 4 + 0][row] = v.x; As[qc * 4 + 1][row] = v.y;
      As[qc * 4 + 2][row] = v.z; As[qc * 4 + 3][row] = v.w;
    }
#pragma unroll
    for (int i = 0; i < 2; ++i) {
      int li = tid + i * 256;
      int kk = li >> 5, c4 = li & 31;
      int c = k0 + kk;
      const float* src = (c < D1_) ? (p1 + ((size_t)b * D1_ + c) * N_)
                                   : (interp + ((size_t)b * D2_ + (c - D1_)) * N_);
      *(float4*)&Bs[kk][c4 * 4] = *(const float4*)(src + bn0 + c4 * 4);
    }
    __syncthreads();
#pragma unroll
    for (int k = 0; k < 16; ++k) {
      float a[8], bb[8];
      *(float4*)&a[0]  = *(const float4*)&As[k][ty * 4];
      *(float4*)&a[4]  = *(const float4*)&As[k][64 + ty * 4];
      *(float4*)&bb[0] = *(const float4*)&Bs[k][tx * 4];
      *(float4*)&bb[4] = *(const float4*)&Bs[k][64 + tx * 4];
#pragma unroll
      for (int i = 0; i < 8; ++i)
#pragma unroll
        for (int j = 0; j < 8; ++j) acc[i][j] = fmaf(a[i], bb[j], acc[i][j]);
    }
  }
#pragma unroll
  for (int i = 0; i < 8; ++i) {
    int o = bm0 + ty * 4 + (i & 3) + (i >> 2) * 64;
    float bv = bias[o];
    float* dst = y1 + ((size_t)b * CMID_ + o) * N_ + bn0;
    float4 v0 = make_float4(acc[i][0] + bv, acc[i][1] + bv, acc[i][2] + bv, acc[i][3] + bv);
    float4 v1 = make_float4(acc[i][4] + bv, acc[i][5] + bv, acc[i][6] + bv, acc[i][7] + bv);
    *(float4*)(dst + tx * 4) = v0;
    *(float4*)(dst + 64 + tx * 4) = v1;
  }
}

// ---------------------------------------------------------------------------
// GEMM2: same tiling; B-tile staging applies BN1 affine + ReLU on the fly.
// ---------------------------------------------------------------------------
__global__ __launch_bounds__(256) void k_gemm2(const float* __restrict__ W,
                                               const float* __restrict__ bias,
                                               const float* __restrict__ y1,
                                               const float* __restrict__ scale1,
                                               const float* __restrict__ shift1,
                                               float* __restrict__ out) {
  __shared__ float As[16][132];
  __shared__ float Bs[16][128];
  const int b = blockIdx.z;
  const int bm0 = blockIdx.y * 128;
  const int bn0 = blockIdx.x * 128;
  const int tid = threadIdx.x;
  const int tx = tid & 15, ty = tid >> 4;

  float acc[8][8];
  for (int i = 0; i < 8; ++i)
    for (int j = 0; j < 8; ++j) acc[i][j] = 0.f;

  for (int k0 = 0; k0 < CMID_; k0 += 16) {
    __syncthreads();
#pragma unroll
    for (int i = 0; i < 2; ++i) {
      int li = tid + i * 256;
      int row = li >> 2, qc = li & 3;
      float4 v = *(const float4*)(W + (size_t)(bm0 + row) * CMID_ + k0 + qc * 4);
      As[qc * 4 + 0][row] = v.x; As[qc * 4 + 1][row] = v.y;
      As[qc * 4 + 2][row] = v.z; As[qc * 4 + 3][row] = v.w;
    }
#pragma unroll
    for (int i = 0; i < 2; ++i) {
      int li = tid + i * 256;
      int kk = li >> 5, c4 = li & 31;
      int c = k0 + kk;
      float sc = scale1[c], sh = shift1[c];
      float4 v = *(const float4*)(y1 + ((size_t)b * CMID_ + c) * N_ + bn0 + c4 * 4);
      v.x = fmaxf(fmaf(v.x, sc, sh), 0.f);
      v.y = fmaxf(fmaf(v.y, sc, sh), 0.f);
      v.z = fmaxf(fmaf(v.z, sc, sh), 0.f);
      v.w = fmaxf(fmaf(v.w, sc, sh), 0.f);
      *(float4*)&Bs[kk][c4 * 4] = v;
    }
    __syncthreads();
#pragma unroll
    for (int k = 0; k < 16; ++k) {
      float a[8], bb[8];
      *(float4*)&a[0]  = *(const float4*)&As[k][ty * 4];
      *(float4*)&a[4]  = *(const float4*)&As[k][64 + ty * 4];
      *(float4*)&bb[0] = *(const float4*)&Bs[k][tx * 4];
      *(float4*)&bb[4] = *(const float4*)&Bs[k][64 + tx * 4];
#pragma unroll
      for (int i = 0; i < 8; ++i)
#pragma unroll
        for (int j = 0; j < 8; ++j) acc[i][j] = fmaf(a[i], bb[j], acc[i][j]);
    }
  }
#pragma unroll
  for (int i = 0; i < 8; ++i) {
    int o = bm0 + ty * 4 + (i & 3) + (i >> 2) * 64;
    float bv = bias[o];
    float* dst = out + ((size_t)b * COUT_ + o) * N_ + bn0;
    float4 v0 = make_float4(acc[i][0] + bv, acc[i][1] + bv, acc[i][2] + bv, acc[i][3] + bv);
    float4 v1 = make_float4(acc[i][4] + bv, acc[i][5] + bv, acc[i][6] + bv, acc[i][7] + bv);
    *(float4*)(dst + tx * 4) = v0;
    *(float4*)(dst + 64 + tx * 4) = v1;
  }
}

// ---------------------------------------------------------------------------
// Per-channel sum / sumsq over (B,N). One block per (o,b) row.
// ---------------------------------------------------------------------------
__global__ __launch_bounds__(256) void k_stats(const float* __restrict__ y,
                                               float* __restrict__ sum,
                                               float* __restrict__ sumsq) {
  const int o = blockIdx.x, b = blockIdx.y;
  const float4* row = (const float4*)(y + ((size_t)b * 256 + o) * N_);
  float s = 0.f, ss = 0.f;
  for (int i = threadIdx.x; i < N_ / 4; i += 256) {
    float4 v = row[i];
    s  += v.x + v.y + v.z + v.w;
    ss += v.x * v.x + v.y * v.y + v.z * v.z + v.w * v.w;
  }
  for (int off = 32; off; off >>= 1) {
    s  += __shfl_down(s, off);
    ss += __shfl_down(ss, off);
  }
  __shared__ float red[8];
  int w = threadIdx.x >> 6, lane = threadIdx.x & 63;
  if (lane == 0) { red[w] = s; red[4 + w] = ss; }
  __syncthreads();
  if (threadIdx.x == 0) {
    float S  = red[0] + red[1] + red[2] + red[3];
    float SS = red[4] + red[5] + red[6] + red[7];
    atomicAdd(&sum[o], S);
    atomicAdd(&sumsq[o], SS);
  }
}

__global__ __launch_bounds__(256) void k_affine(const float* __restrict__ sum,
                                                const float* __restrict__ sumsq,
                                                const float* __restrict__ g,
                                                const float* __restrict__ beta,
                                                float* __restrict__ scale,
                                                float* __restrict__ shift) {
  int o = threadIdx.x;
  const float inv = 1.0f / (float)(B_ * N_);
  float m = sum[o] * inv;
  float var = sumsq[o] * inv - m * m;
  float sc = g[o] / sqrtf(var + 1e-5f);
  scale[o] = sc;
  shift[o] = beta[o] - m * sc;
}

__global__ __launch_bounds__(256) void k_bn2(float* __restrict__ y,
                                             const float* __restrict__ scale,
                                             const float* __restrict__ shift) {
  const int o = blockIdx.x, b = blockIdx.y;
  float sc = scale[o], sh = shift[o];
  float4* row = (float4*)(y + ((size_t)b * COUT_ + o) * N_);
  for (int i = threadIdx.x; i < N_ / 4; i += 256) {
    float4 v = row[i];
    v.x = fmaxf(fmaf(v.x, sc, sh), 0.f);
    v.y = fmaxf(fmaf(v.y, sc, sh), 0.f);
    v.z = fmaxf(fmaf(v.z, sc, sh), 0.f);
    v.w = fmaxf(fmaf(v.w, sc, sh), 0.f);
    row[i] = v;
  }
}

// ---------------------------------------------------------------------------
extern "C" void kernel_launch(void* const* d_in, const int* in_sizes, int n_in,
                              void* d_out, int out_size, void* d_ws, size_t ws_size,
                              hipStream_t stream) {
  const float* xyz1    = (const float*)d_in[0];
  const float* xyz2    = (const float*)d_in[1];
  const float* points1 = (const float*)d_in[2];
  const float* points2 = (const float*)d_in[3];
  const float* w1      = (const float*)d_in[4];
  const float* b1      = (const float*)d_in[5];
  const float* g1      = (const float*)d_in[6];
  const float* beta1   = (const float*)d_in[7];
  const float* w2      = (const float*)d_in[8];
  const float* b2      = (const float*)d_in[9];
  const float* g2      = (const float*)d_in[10];
  const float* beta2   = (const float*)d_in[11];
  float* out = (float*)d_out;

  char* ws = (char*)d_ws;
  const size_t big = (size_t)B_ * D2_ * N_ * sizeof(float);  // 64 MB
  int4*   idx4   = (int4*)ws;                       // 1 MB
  float4* w4     = (float4*)(ws + (1 << 20));       // 1 MB
  float*  interp = (float*)(ws + (2 << 20));        // 64 MB
  float*  y1     = (float*)(ws + (2 << 20) + big);  // 64 MB
  float*  stats  = (float*)(ws + (2 << 20) + 2 * big);
  // stats layout (floats): [0]=sum1 [256]=sumsq1 [512]=sum2 [768]=sumsq2
  //                        [1024]=scale1 [1280]=shift1 [1536]=scale2 [1792]=shift2

  hipMemsetAsync(stats, 0, 1024 * sizeof(float), stream);

  k_nn    <<<dim3(N_ / 256, B_), 256, 0, stream>>>(xyz1, xyz2, idx4, w4);
  k_interp<<<dim3(D2_ / 4, B_), 256, 0, stream>>>(points2, idx4, w4, interp);
  k_gemm1 <<<dim3(N_ / 128, CMID_ / 128, B_), 256, 0, stream>>>(w1, b1, points1, interp, y1);
  k_stats <<<dim3(CMID_, B_), 256, 0, stream>>>(y1, stats + 0, stats + 256);
  k_affine<<<1, 256, 0, stream>>>(stats + 0, stats + 256, g1, beta1, stats + 1024, stats + 1280);
  k_gemm2 <<<dim3(N_ / 128, COUT_ / 128, B_), 256, 0, stream>>>(w2, b2, y1, stats + 1024, stats + 1280, out);
  k_stats <<<dim3(COUT_, B_), 256, 0, stream>>>(out, stats + 512, stats + 768);
  k_affine<<<1, 256, 0, stream>>>(stats + 512, stats + 768, g2, beta2, stats + 1536, stats + 1792);
  k_bn2   <<<dim3(COUT_, B_), 256, 0, stream>>>(out, stats + 1536, stats + 1792);
}

// Round 2
// 392.330 us; speedup vs baseline: 1.6217x; 1.6217x over previous
//
#include <hip/hip_runtime.h>

#define B_    8
#define N_    8192
#define S_    2048
#define D1_   128
#define D2_   256
#define CIN_  384
#define CMID_ 256
#define COUT_ 256

typedef unsigned int  u32;
typedef unsigned short u16;
typedef __attribute__((ext_vector_type(8))) short short8;
typedef __attribute__((ext_vector_type(4))) float f32x4;

static __device__ __forceinline__ u32 uminu(u32 a, u32 b) { return a < b ? a : b; }
static __device__ __forceinline__ u32 umaxu(u32 a, u32 b) { return a > b ? a : b; }
// compiles to v_med3_u32 via pattern match
static __device__ __forceinline__ u32 umed3(u32 a, u32 b, u32 c) {
  return umaxu(uminu(a, b), uminu(umaxu(a, b), c));
}
static __device__ __forceinline__ u16 f2bf(float f) {
  union { float f; u32 u; } v; v.f = f;
  u32 r = v.u + 0x7FFFu + ((v.u >> 16) & 1u);  // RNE
  return (u16)(r >> 16);
}
static __device__ __forceinline__ float bflo(u32 u) { return __uint_as_float(u << 16); }
static __device__ __forceinline__ float bfhi(u32 u) { return __uint_as_float(u & 0xFFFF0000u); }

#define GLD16(g, l)                                                             \
  __builtin_amdgcn_global_load_lds((const __attribute__((address_space(1))) void*)(g), \
                                   (__attribute__((address_space(3))) void*)(l), 16, 0, 0)

// ---------------------------------------------------------------------------
// Prep: pts4[b][s] = (-2x, -2y, -2z, |q|^2_f32)   (xyz recoverable exactly)
// ---------------------------------------------------------------------------
__global__ __launch_bounds__(256) void k_prep(const float* __restrict__ xyz2,
                                              float4* __restrict__ pts4) {
  const int b = blockIdx.y, s = blockIdx.x * 256 + threadIdx.x;
  const float* xb = xyz2 + (size_t)b * 3 * S_;
  float x = xb[s], y = xb[S_ + s], z = xb[2 * S_ + s];
  pts4[b * S_ + s] = make_float4(-2.f * x, -2.f * y, -2.f * z, x * x + y * y + z * z);
}

// ---------------------------------------------------------------------------
// NN screen: fp32 distance, packed key = (bits & ~0x7FF) | s. Keep sorted
// top-4 per (n, chunk) via min/med3 network. Points read as wave-uniform
// s_loads (no LDS). 4 s-chunks -> 4096 waves (4/SIMD).
// ---------------------------------------------------------------------------
__global__ __launch_bounds__(256) void k_nn_scan(const float* __restrict__ xyz1,
                                                 const float4* __restrict__ pts4,
                                                 uint4* __restrict__ keys) {
  const int b = blockIdx.z, chunk = blockIdx.y;
  const int n = blockIdx.x * 256 + threadIdx.x;
  const float* pb = xyz1 + (size_t)b * 3 * N_;
  const float px = pb[n], py = pb[N_ + n], pz = pb[2 * N_ + n];
  const float pn = px * px + py * py + pz * pz;
  const float4* __restrict__ P = pts4 + b * S_ + chunk * 512;
  const u32 sbase = chunk * 512;
  u32 m0 = ~0u, m1 = ~0u, m2 = ~0u, m3 = ~0u;
#pragma unroll 8
  for (int s = 0; s < 512; ++s) {
    float4 q = P[s];  // uniform address -> s_load_dwordx4
    float d = fmaf(px, q.x, fmaf(py, q.y, fmaf(pz, q.z, pn + q.w)));
    d = fmaxf(d, 0.f);
    u32 k = (__float_as_uint(d) & 0xFFFFF800u) | (sbase + (u32)s);
    m3 = uminu(m3, umaxu(m2, k));   // uses old m2
    m2 = umed3(m1, m2, k);          // old m1, m2
    m1 = umed3(m0, m1, k);          // old m0, m1
    m0 = uminu(m0, k);
  }
  uint4 v; v.x = m0; v.y = m1; v.z = m2; v.w = m3;
  keys[((size_t)(b * 4 + chunk)) * N_ + n] = v;
}

// ---------------------------------------------------------------------------
// Refine: exact fp64 distances (reference formula) over the 16 candidates,
// lexicographic (d, idx) top-3 -> weights. Matches R1's fp64 selection.
// ---------------------------------------------------------------------------
__global__ __launch_bounds__(256) void k_refine(const float* __restrict__ xyz1,
                                                const float4* __restrict__ pts4,
                                                const uint4* __restrict__ keys,
                                                int4* __restrict__ idx4,
                                                float4* __restrict__ w4) {
  const int b = blockIdx.y, n = blockIdx.x * 256 + threadIdx.x;
  const float* pb = xyz1 + (size_t)b * 3 * N_;
  const double px = (double)pb[n], py = (double)pb[N_ + n], pz = (double)pb[2 * N_ + n];
  const double pn = px * px + py * py + pz * pz;
  double bd0 = 1e300, bd1 = 1e300, bd2 = 1e300;
  int bi0 = 1 << 30, bi1 = 1 << 30, bi2 = 1 << 30;
#pragma unroll
  for (int c = 0; c < 4; ++c) {
    uint4 kk = keys[((size_t)(b * 4 + c)) * N_ + n];
    u32 arr[4] = {kk.x, kk.y, kk.z, kk.w};
#pragma unroll
    for (int j = 0; j < 4; ++j) {
      int s = (int)(arr[j] & 2047u);
      float4 q = pts4[b * S_ + s];
      double x = (double)(q.x * -0.5f), y = (double)(q.y * -0.5f), z = (double)(q.z * -0.5f);
      double dot = px * x + py * y + pz * z;
      double d = -2.0 * dot + (pn + (x * x + y * y + z * z));
      if (d < bd2 || (d == bd2 && s < bi2)) {
        if (d < bd1 || (d == bd1 && s < bi1)) {
          bd2 = bd1; bi2 = bi1;
          if (d < bd0 || (d == bd0 && s < bi0)) { bd1 = bd0; bi1 = bi0; bd0 = d; bi0 = s; }
          else                                  { bd1 = d;  bi1 = s; }
        } else { bd2 = d; bi2 = s; }
      }
    }
  }
  float f0 = (float)bd0, f1 = (float)bd1, f2 = (float)bd2;
  float r0 = 1.f / (f0 + 1e-8f), r1 = 1.f / (f1 + 1e-8f), r2 = 1.f / (f2 + 1e-8f);
  float rs = r0 + r1 + r2;
  w4[(size_t)b * N_ + n]   = make_float4(r0 / rs, r1 / rs, r2 / rs, 0.f);
  idx4[(size_t)b * N_ + n] = make_int4(bi0, bi1, bi2, 0);
}

// ---------------------------------------------------------------------------
// Transpose points2 [b][256][2048] -> p2T [b][2048][256]  (fp32, LDS tiles)
// ---------------------------------------------------------------------------
__global__ __launch_bounds__(256) void k_p2t(const float* __restrict__ p2,
                                             float* __restrict__ p2T) {
  __shared__ float t[32][33];
  const int b = blockIdx.z, s0 = blockIdx.x * 32, d0 = blockIdx.y * 32;
  const int cc = threadIdx.x & 31, rr = threadIdx.x >> 5;  // 8 rows/pass
#pragma unroll
  for (int i = 0; i < 4; ++i) {
    int r = rr + i * 8;
    t[r][cc] = p2[((size_t)b * D2_ + d0 + r) * S_ + s0 + cc];
  }
  __syncthreads();
#pragma unroll
  for (int i = 0; i < 4; ++i) {
    int r = rr + i * 8;  // r = s-local
    p2T[((size_t)b * S_ + s0 + r) * D2_ + d0 + cc] = t[cc][r];
  }
}

// ---------------------------------------------------------------------------
// points1 [b][128][N] -> xT[b][n][0..127] bf16 (transpose + convert)
// ---------------------------------------------------------------------------
__global__ __launch_bounds__(256) void k_packp1(const float* __restrict__ p1,
                                                u16* __restrict__ xT) {
  __shared__ float t[32][33];
  const int b = blockIdx.z, n0 = blockIdx.x * 32, c0 = blockIdx.y * 32;
  const int cc = threadIdx.x & 31, rr = threadIdx.x >> 5;
#pragma unroll
  for (int i = 0; i < 4; ++i) {
    int r = rr + i * 8;
    t[r][cc] = p1[((size_t)b * D1_ + c0 + r) * N_ + n0 + cc];
  }
  __syncthreads();
#pragma unroll
  for (int i = 0; i < 4; ++i) {
    int r = rr + i * 8;  // r = n-local
    xT[((size_t)b * N_ + n0 + r) * CIN_ + c0 + cc] = f2bf(t[cc][r]);
  }
}

// ---------------------------------------------------------------------------
// Gather+interp directly into xT[b][n][128..383] bf16 (reads p2T rows, L2-hot)
// ---------------------------------------------------------------------------
__global__ __launch_bounds__(256) void k_gather_pack(const float* __restrict__ p2T,
                                                     const int4* __restrict__ idx4,
                                                     const float4* __restrict__ w4,
                                                     u16* __restrict__ xT) {
  const int b = blockIdx.y, n = blockIdx.x * 256 + threadIdx.x;
  int4 id = idx4[(size_t)b * N_ + n];
  float4 w = w4[(size_t)b * N_ + n];
  const float4* r0 = (const float4*)(p2T + ((size_t)b * S_ + id.x) * D2_);
  const float4* r1 = (const float4*)(p2T + ((size_t)b * S_ + id.y) * D2_);
  const float4* r2 = (const float4*)(p2T + ((size_t)b * S_ + id.z) * D2_);
  u16* dst = xT + ((size_t)b * N_ + n) * CIN_ + D1_;
#pragma unroll 4
  for (int c4 = 0; c4 < D2_ / 4; ++c4) {
    float4 a = r0[c4], bb = r1[c4], cq = r2[c4];
    ushort4 pk;
    pk.x = f2bf(a.x * w.x + bb.x * w.y + cq.x * w.z);
    pk.y = f2bf(a.y * w.x + bb.y * w.y + cq.y * w.z);
    pk.z = f2bf(a.z * w.x + bb.z * w.y + cq.z * w.z);
    pk.w = f2bf(a.w * w.x + bb.w * w.y + cq.w * w.z);
    *(ushort4*)(dst + c4 * 4) = pk;
  }
}

// ---------------------------------------------------------------------------
// Convert w1, w2 to bf16 (row-major, k-contiguous)
// ---------------------------------------------------------------------------
__global__ __launch_bounds__(256) void k_wcvt(const float* __restrict__ w1,
                                              const float* __restrict__ w2,
                                              u16* __restrict__ w1b,
                                              u16* __restrict__ w2b) {
  int i = blockIdx.x * 256 + threadIdx.x;
  if (i < CMID_ * CIN_) w1b[i] = f2bf(w1[i]);
  int j = i - CMID_ * CIN_;
  if (j >= 0 && j < COUT_ * CMID_) w2b[j] = f2bf(w2[j]);
}

// ---------------------------------------------------------------------------
// GEMM1 (bf16 MFMA): y1T[b][n][o] = bf16( w1[o][:] . xT[b][n][:] + b1[o] )
// 128x128 tile, 4 waves (2x2 of 64x64), BK=32, global_load_lds width-16.
// ---------------------------------------------------------------------------
__global__ __launch_bounds__(256) void k_gemm1(const u16* __restrict__ Wb,
                                               const float* __restrict__ bias,
                                               const u16* __restrict__ xT,
                                               u16* __restrict__ y1T) {
  __shared__ u16 As[128 * 32];
  __shared__ u16 Bs[128 * 32];
  const int b = blockIdx.z, bm0 = blockIdx.y * 128, bn0 = blockIdx.x * 128;
  const int tid = threadIdx.x, w = tid >> 6, l = tid & 63;
  const int wm = w & 1, wn = w >> 1;
  const int lr = l >> 2, lc = l & 3;
  const int fm = l & 15, fq = l >> 4;
  f32x4 acc[4][4];
#pragma unroll
  for (int i = 0; i < 4; ++i)
#pragma unroll
    for (int j = 0; j < 4; ++j) acc[i][j] = (f32x4){0.f, 0.f, 0.f, 0.f};

  for (int k0 = 0; k0 < CIN_; k0 += 32) {
    __syncthreads();
#pragma unroll
    for (int j = 0; j < 2; ++j) {
      int seg = w * 2 + j;
      int row = seg * 16 + lr;
      const u16* ga = Wb + (size_t)(bm0 + row) * CIN_ + k0 + lc * 8;
      const u16* gb = xT + ((size_t)b * N_ + bn0 + row) * CIN_ + k0 + lc * 8;
      GLD16(ga, &As[seg * 512]);
      GLD16(gb, &Bs[seg * 512]);
    }
    __syncthreads();
    short8 af[4], bfr[4];
#pragma unroll
    for (int f = 0; f < 4; ++f) {
      af[f]  = *(const short8*)&As[(wm * 64 + f * 16 + fm) * 32 + fq * 8];
      bfr[f] = *(const short8*)&Bs[(wn * 64 + f * 16 + fm) * 32 + fq * 8];
    }
#pragma unroll
    for (int i = 0; i < 4; ++i)
#pragma unroll
      for (int j = 0; j < 4; ++j)
        acc[i][j] = __builtin_amdgcn_mfma_f32_16x16x32_bf16(af[i], bfr[j], acc[i][j], 0, 0, 0);
  }
#pragma unroll
  for (int i = 0; i < 4; ++i) {
    int ob = bm0 + wm * 64 + i * 16 + fq * 4;
    float4 b4 = *(const float4*)(bias + ob);
#pragma unroll
    for (int j = 0; j < 4; ++j) {
      int n = bn0 + wn * 64 + j * 16 + fm;
      ushort4 pk;
      pk.x = f2bf(acc[i][j][0] + b4.x);
      pk.y = f2bf(acc[i][j][1] + b4.y);
      pk.z = f2bf(acc[i][j][2] + b4.z);
      pk.w = f2bf(acc[i][j][3] + b4.w);
      *(ushort4*)(y1T + ((size_t)b * N_ + n) * CMID_ + ob) = pk;
    }
  }
}

// ---------------------------------------------------------------------------
// Stats over y1T bf16 [b][n][256]: per-channel sum/sumsq (fp32 accum)
// ---------------------------------------------------------------------------
__global__ __launch_bounds__(256) void k_stats1(const u16* __restrict__ y1T,
                                                float* __restrict__ sum,
                                                float* __restrict__ sumsq) {
  __shared__ float ls[256], lss[256];
  const int b = blockIdx.y, chunk = blockIdx.x, tid = threadIdx.x;
  ls[tid] = 0.f; lss[tid] = 0.f;
  __syncthreads();
  const int c4 = (tid & 63) * 4, noff = tid >> 6;
  float s0 = 0, s1 = 0, s2 = 0, s3 = 0, q0 = 0, q1 = 0, q2 = 0, q3 = 0;
  for (int i = 0; i < 64; ++i) {
    int n = chunk * 256 + i * 4 + noff;
    ushort4 v = *(const ushort4*)(y1T + ((size_t)b * N_ + n) * CMID_ + c4);
    float f0 = bflo((u32)v.x << 16 >> 16 | ((u32)v.x)), f1, f2, f3;
    // simpler exact unpack:
    f0 = __uint_as_float(((u32)v.x) << 16);
    f1 = __uint_as_float(((u32)v.y) << 16);
    f2 = __uint_as_float(((u32)v.z) << 16);
    f3 = __uint_as_float(((u32)v.w) << 16);
    s0 += f0; s1 += f1; s2 += f2; s3 += f3;
    q0 += f0 * f0; q1 += f1 * f1; q2 += f2 * f2; q3 += f3 * f3;
  }
  atomicAdd(&ls[c4 + 0], s0); atomicAdd(&ls[c4 + 1], s1);
  atomicAdd(&ls[c4 + 2], s2); atomicAdd(&ls[c4 + 3], s3);
  atomicAdd(&lss[c4 + 0], q0); atomicAdd(&lss[c4 + 1], q1);
  atomicAdd(&lss[c4 + 2], q2); atomicAdd(&lss[c4 + 3], q3);
  __syncthreads();
  atomicAdd(&sum[tid], ls[tid]);
  atomicAdd(&sumsq[tid], lss[tid]);
}

__global__ __launch_bounds__(256) void k_affine(const float* __restrict__ sum,
                                                const float* __restrict__ sumsq,
                                                const float* __restrict__ g,
                                                const float* __restrict__ beta,
                                                float* __restrict__ scale,
                                                float* __restrict__ shift) {
  int o = threadIdx.x;
  const float inv = 1.0f / (float)(B_ * N_);
  float m = sum[o] * inv;
  float var = sumsq[o] * inv - m * m;
  float sc = g[o] / sqrtf(var + 1e-5f);
  scale[o] = sc;
  shift[o] = beta[o] - m * sc;
}

// ---------------------------------------------------------------------------
// GEMM2 (bf16 MFMA): out[b][o][n] = w2[o][:] . relu(bn1(y1T[b][n][:])) + b2[o]
// B-staging applies BN1 affine + ReLU, A via global_load_lds. Output fp32.
// ---------------------------------------------------------------------------
__global__ __launch_bounds__(256) void k_gemm2(const u16* __restrict__ Wb2,
                                               const float* __restrict__ b2,
                                               const u16* __restrict__ y1T,
                                               const float* __restrict__ scale,
                                               const float* __restrict__ shift,
                                               float* __restrict__ out) {
  __shared__ u16 As[128 * 32];
  __shared__ u16 Bs[128 * 32];
  const int b = blockIdx.z, bm0 = blockIdx.y * 128, bn0 = blockIdx.x * 128;
  const int tid = threadIdx.x, w = tid >> 6, l = tid & 63;
  const int wm = w & 1, wn = w >> 1;
  const int lr = l >> 2, lc = l & 3;
  const int fm = l & 15, fq = l >> 4;
  f32x4 acc[4][4];
#pragma unroll
  for (int i = 0; i < 4; ++i)
#pragma unroll
    for (int j = 0; j < 4; ++j) acc[i][j] = (f32x4){0.f, 0.f, 0.f, 0.f};

  for (int k0 = 0; k0 < CMID_; k0 += 32) {
    __syncthreads();
#pragma unroll
    for (int j = 0; j < 2; ++j) {
      int seg = w * 2 + j;
      int row = seg * 16 + lr;
      const u16* ga = Wb2 + (size_t)(bm0 + row) * CMID_ + k0 + lc * 8;
      GLD16(ga, &As[seg * 512]);
    }
#pragma unroll
    for (int i = 0; i < 2; ++i) {
      int li = tid + i * 256;          // 0..511 16B-chunks
      int n = li >> 2, cp = li & 3;
      int c = k0 + cp * 8;
      uint4 r = *(const uint4*)(y1T + ((size_t)b * N_ + bn0 + n) * CMID_ + c);
      float4 sA = *(const float4*)(scale + c);
      float4 sB = *(const float4*)(scale + c + 4);
      float4 hA = *(const float4*)(shift + c);
      float4 hB = *(const float4*)(shift + c + 4);
      float v0 = fmaxf(fmaf(bflo(r.x), sA.x, hA.x), 0.f);
      float v1 = fmaxf(fmaf(bfhi(r.x), sA.y, hA.y), 0.f);
      float v2 = fmaxf(fmaf(bflo(r.y), sA.z, hA.z), 0.f);
      float v3 = fmaxf(fmaf(bfhi(r.y), sA.w, hA.w), 0.f);
      float v4 = fmaxf(fmaf(bflo(r.z), sB.x, hB.x), 0.f);
      float v5 = fmaxf(fmaf(bfhi(r.z), sB.y, hB.y), 0.f);
      float v6 = fmaxf(fmaf(bflo(r.w), sB.z, hB.z), 0.f);
      float v7 = fmaxf(fmaf(bfhi(r.w), sB.w, hB.w), 0.f);
      uint4 pk;
      pk.x = (u32)f2bf(v0) | ((u32)f2bf(v1) << 16);
      pk.y = (u32)f2bf(v2) | ((u32)f2bf(v3) << 16);
      pk.z = (u32)f2bf(v4) | ((u32)f2bf(v5) << 16);
      pk.w = (u32)f2bf(v6) | ((u32)f2bf(v7) << 16);
      *(uint4*)&Bs[n * 32 + cp * 8] = pk;
    }
    __syncthreads();
    short8 af[4], bfr[4];
#pragma unroll
    for (int f = 0; f < 4; ++f) {
      af[f]  = *(const short8*)&As[(wm * 64 + f * 16 + fm) * 32 + fq * 8];
      bfr[f] = *(const short8*)&Bs[(wn * 64 + f * 16 + fm) * 32 + fq * 8];
    }
#pragma unroll
    for (int i = 0; i < 4; ++i)
#pragma unroll
      for (int j = 0; j < 4; ++j)
        acc[i][j] = __builtin_amdgcn_mfma_f32_16x16x32_bf16(af[i], bfr[j], acc[i][j], 0, 0, 0);
  }
#pragma unroll
  for (int i = 0; i < 4; ++i) {
    int ob = bm0 + wm * 64 + i * 16 + fq * 4;
    float4 b4 = *(const float4*)(b2 + ob);
#pragma unroll
    for (int j = 0; j < 4; ++j) {
      int n = bn0 + wn * 64 + j * 16 + fm;
      out[((size_t)b * COUT_ + ob + 0) * N_ + n] = acc[i][j][0] + b4.x;
      out[((size_t)b * COUT_ + ob + 1) * N_ + n] = acc[i][j][1] + b4.y;
      out[((size_t)b * COUT_ + ob + 2) * N_ + n] = acc[i][j][2] + b4.z;
      out[((size_t)b * COUT_ + ob + 3) * N_ + n] = acc[i][j][3] + b4.w;
    }
  }
}

// ---------------------------------------------------------------------------
// Per-channel sum / sumsq over (B,N) on fp32 [b][o][n] (layer 2)
// ---------------------------------------------------------------------------
__global__ __launch_bounds__(256) void k_stats(const float* __restrict__ y,
                                               float* __restrict__ sum,
                                               float* __restrict__ sumsq) {
  const int o = blockIdx.x, b = blockIdx.y;
  const float4* row = (const float4*)(y + ((size_t)b * 256 + o) * N_);
  float s = 0.f, ss = 0.f;
  for (int i = threadIdx.x; i < N_ / 4; i += 256) {
    float4 v = row[i];
    s  += v.x + v.y + v.z + v.w;
    ss += v.x * v.x + v.y * v.y + v.z * v.z + v.w * v.w;
  }
  for (int off = 32; off; off >>= 1) {
    s  += __shfl_down(s, off);
    ss += __shfl_down(ss, off);
  }
  __shared__ float red[8];
  int w = threadIdx.x >> 6, lane = threadIdx.x & 63;
  if (lane == 0) { red[w] = s; red[4 + w] = ss; }
  __syncthreads();
  if (threadIdx.x == 0) {
    float S  = red[0] + red[1] + red[2] + red[3];
    float SS = red[4] + red[5] + red[6] + red[7];
    atomicAdd(&sum[o], S);
    atomicAdd(&sumsq[o], SS);
  }
}

__global__ __launch_bounds__(256) void k_bn2(float* __restrict__ y,
                                             const float* __restrict__ scale,
                                             const float* __restrict__ shift) {
  const int o = blockIdx.x, b = blockIdx.y;
  float sc = scale[o], sh = shift[o];
  float4* row = (float4*)(y + ((size_t)b * COUT_ + o) * N_);
  for (int i = threadIdx.x; i < N_ / 4; i += 256) {
    float4 v = row[i];
    v.x = fmaxf(fmaf(v.x, sc, sh), 0.f);
    v.y = fmaxf(fmaf(v.y, sc, sh), 0.f);
    v.z = fmaxf(fmaf(v.z, sc, sh), 0.f);
    v.w = fmaxf(fmaf(v.w, sc, sh), 0.f);
    row[i] = v;
  }
}

// ---------------------------------------------------------------------------
extern "C" void kernel_launch(void* const* d_in, const int* in_sizes, int n_in,
                              void* d_out, int out_size, void* d_ws, size_t ws_size,
                              hipStream_t stream) {
  const float* xyz1    = (const float*)d_in[0];
  const float* xyz2    = (const float*)d_in[1];
  const float* points1 = (const float*)d_in[2];
  const float* points2 = (const float*)d_in[3];
  const float* w1      = (const float*)d_in[4];
  const float* b1      = (const float*)d_in[5];
  const float* g1      = (const float*)d_in[6];
  const float* beta1   = (const float*)d_in[7];
  const float* w2      = (const float*)d_in[8];
  const float* b2      = (const float*)d_in[9];
  const float* g2      = (const float*)d_in[10];
  const float* beta2   = (const float*)d_in[11];
  float* out = (float*)d_out;

  char* ws = (char*)d_ws;
  size_t off = 0;
  u16*    xT    = (u16*)(ws + off);   off += (size_t)B_ * N_ * CIN_ * 2;      // 50.3 MB
  u16*    y1T   = (u16*)(ws + off);   off += (size_t)B_ * N_ * CMID_ * 2;     // 33.6 MB
  float*  p2T   = (float*)(ws + off); off += (size_t)B_ * S_ * D2_ * 4;       // 16.8 MB
  float4* pts4  = (float4*)(ws + off); off += (size_t)B_ * S_ * 16;           // 0.26 MB
  uint4*  keys  = (uint4*)(ws + off); off += (size_t)B_ * 4 * N_ * 16;        // 4 MB
  int4*   idx4  = (int4*)(ws + off);  off += (size_t)B_ * N_ * 16;            // 1 MB
  float4* w4    = (float4*)(ws + off); off += (size_t)B_ * N_ * 16;           // 1 MB
  u16*    w1b   = (u16*)(ws + off);   off += (size_t)CMID_ * CIN_ * 2;
  u16*    w2b   = (u16*)(ws + off);   off += (size_t)COUT_ * CMID_ * 2;
  float*  stats = (float*)(ws + off);
  // stats: [0]=sum1 [256]=sumsq1 [512]=sum2 [768]=sumsq2
  //        [1024]=scale1 [1280]=shift1 [1536]=scale2 [1792]=shift2

  hipMemsetAsync(stats, 0, 1024 * sizeof(float), stream);

  k_wcvt       <<<dim3((CMID_ * CIN_ + COUT_ * CMID_) / 256), 256, 0, stream>>>(w1, w2, w1b, w2b);
  k_prep       <<<dim3(S_ / 256, B_), 256, 0, stream>>>(xyz2, pts4);
  k_p2t        <<<dim3(S_ / 32, D2_ / 32, B_), 256, 0, stream>>>(points2, p2T);
  k_nn_scan    <<<dim3(N_ / 256, 4, B_), 256, 0, stream>>>(xyz1, pts4, keys);
  k_refine     <<<dim3(N_ / 256, B_), 256, 0, stream>>>(xyz1, pts4, keys, idx4, w4);
  k_packp1     <<<dim3(N_ / 32, D1_ / 32, B_), 256, 0, stream>>>(points1, xT);
  k_gather_pack<<<dim3(N_ / 256, B_), 256, 0, stream>>>(p2T, idx4, w4, xT);
  k_gemm1      <<<dim3(N_ / 128, CMID_ / 128, B_), 256, 0, stream>>>(w1b, b1, xT, y1T);
  k_stats1     <<<dim3(N_ / 256, B_), 256, 0, stream>>>(y1T, stats + 0, stats + 256);
  k_affine     <<<1, 256, 0, stream>>>(stats + 0, stats + 256, g1, beta1, stats + 1024, stats + 1280);
  k_gemm2      <<<dim3(N_ / 128, COUT_ / 128, B_), 256, 0, stream>>>(w2b, b2, y1T, stats + 1024, stats + 1280, out);
  k_stats      <<<dim3(COUT_, B_), 256, 0, stream>>>(out, stats + 512, stats + 768);
  k_affine     <<<1, 256, 0, stream>>>(stats + 512, stats + 768, g2, beta2, stats + 1536, stats + 1792);
  k_bn2        <<<dim3(COUT_, B_), 256, 0, stream>>>(out, stats + 1536, stats + 1792);
}

// Round 3
// 309.034 us; speedup vs baseline: 2.0588x; 1.2695x over previous
//
#include <hip/hip_runtime.h>

#define B_    8
#define N_    8192
#define S_    2048
#define D1_   128
#define D2_   256
#define CIN_  384
#define CMID_ 256
#define COUT_ 256

typedef unsigned int  u32;
typedef unsigned short u16;
typedef __attribute__((ext_vector_type(8))) short short8;
typedef __attribute__((ext_vector_type(4))) float f32x4;

static __device__ __forceinline__ u32 uminu(u32 a, u32 b) { return a < b ? a : b; }
static __device__ __forceinline__ u32 umaxu(u32 a, u32 b) { return a > b ? a : b; }
// compiles to v_med3_u32 via pattern match
static __device__ __forceinline__ u32 umed3(u32 a, u32 b, u32 c) {
  return umaxu(uminu(a, b), uminu(umaxu(a, b), c));
}
static __device__ __forceinline__ u16 f2bf(float f) {
  union { float f; u32 u; } v; v.f = f;
  u32 r = v.u + 0x7FFFu + ((v.u >> 16) & 1u);  // RNE
  return (u16)(r >> 16);
}
static __device__ __forceinline__ float bflo(u32 u) { return __uint_as_float(u << 16); }
static __device__ __forceinline__ float bfhi(u32 u) { return __uint_as_float(u & 0xFFFF0000u); }

#define GLD16(g, l)                                                             \
  __builtin_amdgcn_global_load_lds((const __attribute__((address_space(1))) void*)(g), \
                                   (__attribute__((address_space(3))) void*)(l), 16, 0, 0)

// ---------------------------------------------------------------------------
// Prep: pts4[b][s] = (-2x, -2y, -2z, |q|^2_f32)   (xyz recoverable exactly)
// ---------------------------------------------------------------------------
__global__ __launch_bounds__(256) void k_prep(const float* __restrict__ xyz2,
                                              float4* __restrict__ pts4) {
  const int b = blockIdx.y, s = blockIdx.x * 256 + threadIdx.x;
  const float* xb = xyz2 + (size_t)b * 3 * S_;
  float x = xb[s], y = xb[S_ + s], z = xb[2 * S_ + s];
  pts4[b * S_ + s] = make_float4(-2.f * x, -2.f * y, -2.f * z, x * x + y * y + z * z);
}

// ---------------------------------------------------------------------------
// NN screen: fp32 distance, packed key = (bits & ~0x7FF) | s. Keep sorted
// top-4 per (n, chunk) via min/med3 network. Points read as wave-uniform
// s_loads (no LDS). 4 s-chunks -> 4096 waves (4/SIMD).
// ---------------------------------------------------------------------------
__global__ __launch_bounds__(256) void k_nn_scan(const float* __restrict__ xyz1,
                                                 const float4* __restrict__ pts4,
                                                 uint4* __restrict__ keys) {
  const int b = blockIdx.z, chunk = blockIdx.y;
  const int n = blockIdx.x * 256 + threadIdx.x;
  const float* pb = xyz1 + (size_t)b * 3 * N_;
  const float px = pb[n], py = pb[N_ + n], pz = pb[2 * N_ + n];
  const float pn = px * px + py * py + pz * pz;
  const float4* __restrict__ P = pts4 + b * S_ + chunk * 512;
  const u32 sbase = chunk * 512;
  u32 m0 = ~0u, m1 = ~0u, m2 = ~0u, m3 = ~0u;
#pragma unroll 8
  for (int s = 0; s < 512; ++s) {
    float4 q = P[s];  // uniform address -> s_load_dwordx4
    float d = fmaf(px, q.x, fmaf(py, q.y, fmaf(pz, q.z, pn + q.w)));
    d = fmaxf(d, 0.f);
    u32 k = (__float_as_uint(d) & 0xFFFFF800u) | (sbase + (u32)s);
    m3 = uminu(m3, umaxu(m2, k));   // uses old m2
    m2 = umed3(m1, m2, k);          // old m1, m2
    m1 = umed3(m0, m1, k);          // old m0, m1
    m0 = uminu(m0, k);
  }
  uint4 v; v.x = m0; v.y = m1; v.z = m2; v.w = m3;
  keys[((size_t)(b * 4 + chunk)) * N_ + n] = v;
}

// ---------------------------------------------------------------------------
// Refine: exact fp64 distances (reference formula) over the 16 candidates,
// lexicographic (d, idx) top-3 -> weights. Matches R1's fp64 selection.
// ---------------------------------------------------------------------------
__global__ __launch_bounds__(256) void k_refine(const float* __restrict__ xyz1,
                                                const float4* __restrict__ pts4,
                                                const uint4* __restrict__ keys,
                                                int4* __restrict__ idx4,
                                                float4* __restrict__ w4) {
  const int b = blockIdx.y, n = blockIdx.x * 256 + threadIdx.x;
  const float* pb = xyz1 + (size_t)b * 3 * N_;
  const double px = (double)pb[n], py = (double)pb[N_ + n], pz = (double)pb[2 * N_ + n];
  const double pn = px * px + py * py + pz * pz;
  double bd0 = 1e300, bd1 = 1e300, bd2 = 1e300;
  int bi0 = 1 << 30, bi1 = 1 << 30, bi2 = 1 << 30;
#pragma unroll
  for (int c = 0; c < 4; ++c) {
    uint4 kk = keys[((size_t)(b * 4 + c)) * N_ + n];
    u32 arr[4] = {kk.x, kk.y, kk.z, kk.w};
#pragma unroll
    for (int j = 0; j < 4; ++j) {
      int s = (int)(arr[j] & 2047u);
      float4 q = pts4[b * S_ + s];
      double x = (double)(q.x * -0.5f), y = (double)(q.y * -0.5f), z = (double)(q.z * -0.5f);
      double dot = px * x + py * y + pz * z;
      double d = -2.0 * dot + (pn + (x * x + y * y + z * z));
      if (d < bd2 || (d == bd2 && s < bi2)) {
        if (d < bd1 || (d == bd1 && s < bi1)) {
          bd2 = bd1; bi2 = bi1;
          if (d < bd0 || (d == bd0 && s < bi0)) { bd1 = bd0; bi1 = bi0; bd0 = d; bi0 = s; }
          else                                  { bd1 = d;  bi1 = s; }
        } else { bd2 = d; bi2 = s; }
      }
    }
  }
  float f0 = (float)bd0, f1 = (float)bd1, f2 = (float)bd2;
  float r0 = 1.f / (f0 + 1e-8f), r1 = 1.f / (f1 + 1e-8f), r2 = 1.f / (f2 + 1e-8f);
  float rs = r0 + r1 + r2;
  w4[(size_t)b * N_ + n]   = make_float4(r0 / rs, r1 / rs, r2 / rs, 0.f);
  idx4[(size_t)b * N_ + n] = make_int4(bi0, bi1, bi2, 0);
}

// ---------------------------------------------------------------------------
// Transpose points2 [b][256][2048] -> p2T [b][2048][256]  (fp32, LDS tiles)
// ---------------------------------------------------------------------------
__global__ __launch_bounds__(256) void k_p2t(const float* __restrict__ p2,
                                             float* __restrict__ p2T) {
  __shared__ float t[32][33];
  const int b = blockIdx.z, s0 = blockIdx.x * 32, d0 = blockIdx.y * 32;
  const int cc = threadIdx.x & 31, rr = threadIdx.x >> 5;  // 8 rows/pass
#pragma unroll
  for (int i = 0; i < 4; ++i) {
    int r = rr + i * 8;
    t[r][cc] = p2[((size_t)b * D2_ + d0 + r) * S_ + s0 + cc];
  }
  __syncthreads();
#pragma unroll
  for (int i = 0; i < 4; ++i) {
    int r = rr + i * 8;  // r = s-local
    p2T[((size_t)b * S_ + s0 + r) * D2_ + d0 + cc] = t[cc][r];
  }
}

// ---------------------------------------------------------------------------
// points1 [b][128][N] -> xT[b][n][0..127] bf16 (transpose + convert)
// ---------------------------------------------------------------------------
__global__ __launch_bounds__(256) void k_packp1(const float* __restrict__ p1,
                                                u16* __restrict__ xT) {
  __shared__ float t[32][33];
  const int b = blockIdx.z, n0 = blockIdx.x * 32, c0 = blockIdx.y * 32;
  const int cc = threadIdx.x & 31, rr = threadIdx.x >> 5;
#pragma unroll
  for (int i = 0; i < 4; ++i) {
    int r = rr + i * 8;
    t[r][cc] = p1[((size_t)b * D1_ + c0 + r) * N_ + n0 + cc];
  }
  __syncthreads();
#pragma unroll
  for (int i = 0; i < 4; ++i) {
    int r = rr + i * 8;  // r = n-local
    xT[((size_t)b * N_ + n0 + r) * CIN_ + c0 + cc] = f2bf(t[cc][r]);
  }
}

// ---------------------------------------------------------------------------
// Gather+interp into xT[b][n][128..383] bf16.
// One WAVE per point n: 64 lanes span the 256 channels (float4/lane), so each
// of the 3 gathered rows is a single coalesced 1KB wave-read; idx/w are
// wave-uniform broadcasts. 4 n per wave (ILP), grid = (N/16, B) = 4096 blocks.
// ---------------------------------------------------------------------------
__global__ __launch_bounds__(256) void k_gather_pack(const float* __restrict__ p2T,
                                                     const int4* __restrict__ idx4,
                                                     const float4* __restrict__ w4,
                                                     u16* __restrict__ xT) {
  const int b = blockIdx.y;
  const int wv = threadIdx.x >> 6, lane = threadIdx.x & 63;
  const int nbase = blockIdx.x * 16 + wv * 4;
  int4   id[4];
  float4 w[4];
#pragma unroll
  for (int i = 0; i < 4; ++i) {
    id[i] = idx4[(size_t)b * N_ + nbase + i];  // wave-uniform broadcast
    w[i]  = w4[(size_t)b * N_ + nbase + i];
  }
#pragma unroll
  for (int i = 0; i < 4; ++i) {
    const int n = nbase + i;
    const float4* r0 = (const float4*)(p2T + ((size_t)b * S_ + id[i].x) * D2_) + lane;
    const float4* r1 = (const float4*)(p2T + ((size_t)b * S_ + id[i].y) * D2_) + lane;
    const float4* r2 = (const float4*)(p2T + ((size_t)b * S_ + id[i].z) * D2_) + lane;
    float4 a = *r0, bb = *r1, cq = *r2;
    ushort4 pk;
    pk.x = f2bf(a.x * w[i].x + bb.x * w[i].y + cq.x * w[i].z);
    pk.y = f2bf(a.y * w[i].x + bb.y * w[i].y + cq.y * w[i].z);
    pk.z = f2bf(a.z * w[i].x + bb.z * w[i].y + cq.z * w[i].z);
    pk.w = f2bf(a.w * w[i].x + bb.w * w[i].y + cq.w * w[i].z);
    *(ushort4*)(xT + ((size_t)b * N_ + n) * CIN_ + D1_ + lane * 4) = pk;
  }
}

// ---------------------------------------------------------------------------
// Convert w1, w2 to bf16 (row-major, k-contiguous)
// ---------------------------------------------------------------------------
__global__ __launch_bounds__(256) void k_wcvt(const float* __restrict__ w1,
                                              const float* __restrict__ w2,
                                              u16* __restrict__ w1b,
                                              u16* __restrict__ w2b) {
  int i = blockIdx.x * 256 + threadIdx.x;
  if (i < CMID_ * CIN_) w1b[i] = f2bf(w1[i]);
  int j = i - CMID_ * CIN_;
  if (j >= 0 && j < COUT_ * CMID_) w2b[j] = f2bf(w2[j]);
}

// ---------------------------------------------------------------------------
// GEMM1 (bf16 MFMA): y1T[b][n][o] = bf16( w1[o][:] . xT[b][n][:] + b1[o] )
// 128x128 tile, 4 waves (2x2 of 64x64), BK=32, global_load_lds width-16.
// ---------------------------------------------------------------------------
__global__ __launch_bounds__(256) void k_gemm1(const u16* __restrict__ Wb,
                                               const float* __restrict__ bias,
                                               const u16* __restrict__ xT,
                                               u16* __restrict__ y1T) {
  __shared__ u16 As[128 * 32];
  __shared__ u16 Bs[128 * 32];
  const int b = blockIdx.z, bm0 = blockIdx.y * 128, bn0 = blockIdx.x * 128;
  const int tid = threadIdx.x, w = tid >> 6, l = tid & 63;
  const int wm = w & 1, wn = w >> 1;
  const int lr = l >> 2, lc = l & 3;
  const int fm = l & 15, fq = l >> 4;
  f32x4 acc[4][4];
#pragma unroll
  for (int i = 0; i < 4; ++i)
#pragma unroll
    for (int j = 0; j < 4; ++j) acc[i][j] = (f32x4){0.f, 0.f, 0.f, 0.f};

  for (int k0 = 0; k0 < CIN_; k0 += 32) {
    __syncthreads();
#pragma unroll
    for (int j = 0; j < 2; ++j) {
      int seg = w * 2 + j;
      int row = seg * 16 + lr;
      const u16* ga = Wb + (size_t)(bm0 + row) * CIN_ + k0 + lc * 8;
      const u16* gb = xT + ((size_t)b * N_ + bn0 + row) * CIN_ + k0 + lc * 8;
      GLD16(ga, &As[seg * 512]);
      GLD16(gb, &Bs[seg * 512]);
    }
    __syncthreads();
    short8 af[4], bfr[4];
#pragma unroll
    for (int f = 0; f < 4; ++f) {
      af[f]  = *(const short8*)&As[(wm * 64 + f * 16 + fm) * 32 + fq * 8];
      bfr[f] = *(const short8*)&Bs[(wn * 64 + f * 16 + fm) * 32 + fq * 8];
    }
#pragma unroll
    for (int i = 0; i < 4; ++i)
#pragma unroll
      for (int j = 0; j < 4; ++j)
        acc[i][j] = __builtin_amdgcn_mfma_f32_16x16x32_bf16(af[i], bfr[j], acc[i][j], 0, 0, 0);
  }
#pragma unroll
  for (int i = 0; i < 4; ++i) {
    int ob = bm0 + wm * 64 + i * 16 + fq * 4;
    float4 b4 = *(const float4*)(bias + ob);
#pragma unroll
    for (int j = 0; j < 4; ++j) {
      int n = bn0 + wn * 64 + j * 16 + fm;
      ushort4 pk;
      pk.x = f2bf(acc[i][j][0] + b4.x);
      pk.y = f2bf(acc[i][j][1] + b4.y);
      pk.z = f2bf(acc[i][j][2] + b4.z);
      pk.w = f2bf(acc[i][j][3] + b4.w);
      *(ushort4*)(y1T + ((size_t)b * N_ + n) * CMID_ + ob) = pk;
    }
  }
}

// ---------------------------------------------------------------------------
// Stats over y1T bf16 [b][n][256]: per-channel sum/sumsq (fp32 accum)
// ---------------------------------------------------------------------------
__global__ __launch_bounds__(256) void k_stats1(const u16* __restrict__ y1T,
                                                float* __restrict__ sum,
                                                float* __restrict__ sumsq) {
  __shared__ float ls[256], lss[256];
  const int b = blockIdx.y, chunk = blockIdx.x, tid = threadIdx.x;
  ls[tid] = 0.f; lss[tid] = 0.f;
  __syncthreads();
  const int c4 = (tid & 63) * 4, noff = tid >> 6;
  float s0 = 0, s1 = 0, s2 = 0, s3 = 0, q0 = 0, q1 = 0, q2 = 0, q3 = 0;
  for (int i = 0; i < 64; ++i) {
    int n = chunk * 256 + i * 4 + noff;
    ushort4 v = *(const ushort4*)(y1T + ((size_t)b * N_ + n) * CMID_ + c4);
    float f0 = __uint_as_float(((u32)v.x) << 16);
    float f1 = __uint_as_float(((u32)v.y) << 16);
    float f2 = __uint_as_float(((u32)v.z) << 16);
    float f3 = __uint_as_float(((u32)v.w) << 16);
    s0 += f0; s1 += f1; s2 += f2; s3 += f3;
    q0 += f0 * f0; q1 += f1 * f1; q2 += f2 * f2; q3 += f3 * f3;
  }
  atomicAdd(&ls[c4 + 0], s0); atomicAdd(&ls[c4 + 1], s1);
  atomicAdd(&ls[c4 + 2], s2); atomicAdd(&ls[c4 + 3], s3);
  atomicAdd(&lss[c4 + 0], q0); atomicAdd(&lss[c4 + 1], q1);
  atomicAdd(&lss[c4 + 2], q2); atomicAdd(&lss[c4 + 3], q3);
  __syncthreads();
  atomicAdd(&sum[tid], ls[tid]);
  atomicAdd(&sumsq[tid], lss[tid]);
}

__global__ __launch_bounds__(256) void k_affine(const float* __restrict__ sum,
                                                const float* __restrict__ sumsq,
                                                const float* __restrict__ g,
                                                const float* __restrict__ beta,
                                                float* __restrict__ scale,
                                                float* __restrict__ shift) {
  int o = threadIdx.x;
  const float inv = 1.0f / (float)(B_ * N_);
  float m = sum[o] * inv;
  float var = sumsq[o] * inv - m * m;
  float sc = g[o] / sqrtf(var + 1e-5f);
  scale[o] = sc;
  shift[o] = beta[o] - m * sc;
}

// ---------------------------------------------------------------------------
// GEMM2 (bf16 MFMA): out[b][o][n] = w2[o][:] . relu(bn1(y1T[b][n][:])) + b2[o]
// B-staging applies BN1 affine + ReLU, A via global_load_lds. Output fp32.
// ---------------------------------------------------------------------------
__global__ __launch_bounds__(256) void k_gemm2(const u16* __restrict__ Wb2,
                                               const float* __restrict__ b2,
                                               const u16* __restrict__ y1T,
                                               const float* __restrict__ scale,
                                               const float* __restrict__ shift,
                                               float* __restrict__ out) {
  __shared__ u16 As[128 * 32];
  __shared__ u16 Bs[128 * 32];
  const int b = blockIdx.z, bm0 = blockIdx.y * 128, bn0 = blockIdx.x * 128;
  const int tid = threadIdx.x, w = tid >> 6, l = tid & 63;
  const int wm = w & 1, wn = w >> 1;
  const int lr = l >> 2, lc = l & 3;
  const int fm = l & 15, fq = l >> 4;
  f32x4 acc[4][4];
#pragma unroll
  for (int i = 0; i < 4; ++i)
#pragma unroll
    for (int j = 0; j < 4; ++j) acc[i][j] = (f32x4){0.f, 0.f, 0.f, 0.f};

  for (int k0 = 0; k0 < CMID_; k0 += 32) {
    __syncthreads();
#pragma unroll
    for (int j = 0; j < 2; ++j) {
      int seg = w * 2 + j;
      int row = seg * 16 + lr;
      const u16* ga = Wb2 + (size_t)(bm0 + row) * CMID_ + k0 + lc * 8;
      GLD16(ga, &As[seg * 512]);
    }
#pragma unroll
    for (int i = 0; i < 2; ++i) {
      int li = tid + i * 256;          // 0..511 16B-chunks
      int n = li >> 2, cp = li & 3;
      int c = k0 + cp * 8;
      uint4 r = *(const uint4*)(y1T + ((size_t)b * N_ + bn0 + n) * CMID_ + c);
      float4 sA = *(const float4*)(scale + c);
      float4 sB = *(const float4*)(scale + c + 4);
      float4 hA = *(const float4*)(shift + c);
      float4 hB = *(const float4*)(shift + c + 4);
      float v0 = fmaxf(fmaf(bflo(r.x), sA.x, hA.x), 0.f);
      float v1 = fmaxf(fmaf(bfhi(r.x), sA.y, hA.y), 0.f);
      float v2 = fmaxf(fmaf(bflo(r.y), sA.z, hA.z), 0.f);
      float v3 = fmaxf(fmaf(bfhi(r.y), sA.w, hA.w), 0.f);
      float v4 = fmaxf(fmaf(bflo(r.z), sB.x, hB.x), 0.f);
      float v5 = fmaxf(fmaf(bfhi(r.z), sB.y, hB.y), 0.f);
      float v6 = fmaxf(fmaf(bflo(r.w), sB.z, hB.z), 0.f);
      float v7 = fmaxf(fmaf(bfhi(r.w), sB.w, hB.w), 0.f);
      uint4 pk;
      pk.x = (u32)f2bf(v0) | ((u32)f2bf(v1) << 16);
      pk.y = (u32)f2bf(v2) | ((u32)f2bf(v3) << 16);
      pk.z = (u32)f2bf(v4) | ((u32)f2bf(v5) << 16);
      pk.w = (u32)f2bf(v6) | ((u32)f2bf(v7) << 16);
      *(uint4*)&Bs[n * 32 + cp * 8] = pk;
    }
    __syncthreads();
    short8 af[4], bfr[4];
#pragma unroll
    for (int f = 0; f < 4; ++f) {
      af[f]  = *(const short8*)&As[(wm * 64 + f * 16 + fm) * 32 + fq * 8];
      bfr[f] = *(const short8*)&Bs[(wn * 64 + f * 16 + fm) * 32 + fq * 8];
    }
#pragma unroll
    for (int i = 0; i < 4; ++i)
#pragma unroll
      for (int j = 0; j < 4; ++j)
        acc[i][j] = __builtin_amdgcn_mfma_f32_16x16x32_bf16(af[i], bfr[j], acc[i][j], 0, 0, 0);
  }
#pragma unroll
  for (int i = 0; i < 4; ++i) {
    int ob = bm0 + wm * 64 + i * 16 + fq * 4;
    float4 b4 = *(const float4*)(b2 + ob);
#pragma unroll
    for (int j = 0; j < 4; ++j) {
      int n = bn0 + wn * 64 + j * 16 + fm;
      out[((size_t)b * COUT_ + ob + 0) * N_ + n] = acc[i][j][0] + b4.x;
      out[((size_t)b * COUT_ + ob + 1) * N_ + n] = acc[i][j][1] + b4.y;
      out[((size_t)b * COUT_ + ob + 2) * N_ + n] = acc[i][j][2] + b4.z;
      out[((size_t)b * COUT_ + ob + 3) * N_ + n] = acc[i][j][3] + b4.w;
    }
  }
}

// ---------------------------------------------------------------------------
// Per-channel sum / sumsq over (B,N) on fp32 [b][o][n] (layer 2)
// ---------------------------------------------------------------------------
__global__ __launch_bounds__(256) void k_stats(const float* __restrict__ y,
                                               float* __restrict__ sum,
                                               float* __restrict__ sumsq) {
  const int o = blockIdx.x, b = blockIdx.y;
  const float4* row = (const float4*)(y + ((size_t)b * 256 + o) * N_);
  float s = 0.f, ss = 0.f;
  for (int i = threadIdx.x; i < N_ / 4; i += 256) {
    float4 v = row[i];
    s  += v.x + v.y + v.z + v.w;
    ss += v.x * v.x + v.y * v.y + v.z * v.z + v.w * v.w;
  }
  for (int off = 32; off; off >>= 1) {
    s  += __shfl_down(s, off);
    ss += __shfl_down(ss, off);
  }
  __shared__ float red[8];
  int w = threadIdx.x >> 6, lane = threadIdx.x & 63;
  if (lane == 0) { red[w] = s; red[4 + w] = ss; }
  __syncthreads();
  if (threadIdx.x == 0) {
    float S  = red[0] + red[1] + red[2] + red[3];
    float SS = red[4] + red[5] + red[6] + red[7];
    atomicAdd(&sum[o], S);
    atomicAdd(&sumsq[o], SS);
  }
}

__global__ __launch_bounds__(256) void k_bn2(float* __restrict__ y,
                                             const float* __restrict__ scale,
                                             const float* __restrict__ shift) {
  const int o = blockIdx.x, b = blockIdx.y;
  float sc = scale[o], sh = shift[o];
  float4* row = (float4*)(y + ((size_t)b * COUT_ + o) * N_);
  for (int i = threadIdx.x; i < N_ / 4; i += 256) {
    float4 v = row[i];
    v.x = fmaxf(fmaf(v.x, sc, sh), 0.f);
    v.y = fmaxf(fmaf(v.y, sc, sh), 0.f);
    v.z = fmaxf(fmaf(v.z, sc, sh), 0.f);
    v.w = fmaxf(fmaf(v.w, sc, sh), 0.f);
    row[i] = v;
  }
}

// ---------------------------------------------------------------------------
extern "C" void kernel_launch(void* const* d_in, const int* in_sizes, int n_in,
                              void* d_out, int out_size, void* d_ws, size_t ws_size,
                              hipStream_t stream) {
  const float* xyz1    = (const float*)d_in[0];
  const float* xyz2    = (const float*)d_in[1];
  const float* points1 = (const float*)d_in[2];
  const float* points2 = (const float*)d_in[3];
  const float* w1      = (const float*)d_in[4];
  const float* b1      = (const float*)d_in[5];
  const float* g1      = (const float*)d_in[6];
  const float* beta1   = (const float*)d_in[7];
  const float* w2      = (const float*)d_in[8];
  const float* b2      = (const float*)d_in[9];
  const float* g2      = (const float*)d_in[10];
  const float* beta2   = (const float*)d_in[11];
  float* out = (float*)d_out;

  char* ws = (char*)d_ws;
  size_t off = 0;
  u16*    xT    = (u16*)(ws + off);   off += (size_t)B_ * N_ * CIN_ * 2;      // 50.3 MB
  u16*    y1T   = (u16*)(ws + off);   off += (size_t)B_ * N_ * CMID_ * 2;     // 33.6 MB
  float*  p2T   = (float*)(ws + off); off += (size_t)B_ * S_ * D2_ * 4;       // 16.8 MB
  float4* pts4  = (float4*)(ws + off); off += (size_t)B_ * S_ * 16;           // 0.26 MB
  uint4*  keys  = (uint4*)(ws + off); off += (size_t)B_ * 4 * N_ * 16;        // 4 MB
  int4*   idx4  = (int4*)(ws + off);  off += (size_t)B_ * N_ * 16;            // 1 MB
  float4* w4    = (float4*)(ws + off); off += (size_t)B_ * N_ * 16;           // 1 MB
  u16*    w1b   = (u16*)(ws + off);   off += (size_t)CMID_ * CIN_ * 2;
  u16*    w2b   = (u16*)(ws + off);   off += (size_t)COUT_ * CMID_ * 2;
  float*  stats = (float*)(ws + off);
  // stats: [0]=sum1 [256]=sumsq1 [512]=sum2 [768]=sumsq2
  //        [1024]=scale1 [1280]=shift1 [1536]=scale2 [1792]=shift2

  hipMemsetAsync(stats, 0, 1024 * sizeof(float), stream);

  k_wcvt       <<<dim3((CMID_ * CIN_ + COUT_ * CMID_) / 256), 256, 0, stream>>>(w1, w2, w1b, w2b);
  k_prep       <<<dim3(S_ / 256, B_), 256, 0, stream>>>(xyz2, pts4);
  k_p2t        <<<dim3(S_ / 32, D2_ / 32, B_), 256, 0, stream>>>(points2, p2T);
  k_nn_scan    <<<dim3(N_ / 256, 4, B_), 256, 0, stream>>>(xyz1, pts4, keys);
  k_refine     <<<dim3(N_ / 256, B_), 256, 0, stream>>>(xyz1, pts4, keys, idx4, w4);
  k_packp1     <<<dim3(N_ / 32, D1_ / 32, B_), 256, 0, stream>>>(points1, xT);
  k_gather_pack<<<dim3(N_ / 16, B_), 256, 0, stream>>>(p2T, idx4, w4, xT);
  k_gemm1      <<<dim3(N_ / 128, CMID_ / 128, B_), 256, 0, stream>>>(w1b, b1, xT, y1T);
  k_stats1     <<<dim3(N_ / 256, B_), 256, 0, stream>>>(y1T, stats + 0, stats + 256);
  k_affine     <<<1, 256, 0, stream>>>(stats + 0, stats + 256, g1, beta1, stats + 1024, stats + 1280);
  k_gemm2      <<<dim3(N_ / 128, COUT_ / 128, B_), 256, 0, stream>>>(w2b, b2, y1T, stats + 1024, stats + 1280, out);
  k_stats      <<<dim3(COUT_, B_), 256, 0, stream>>>(out, stats + 512, stats + 768);
  k_affine     <<<1, 256, 0, stream>>>(stats + 512, stats + 768, g2, beta2, stats + 1536, stats + 1792);
  k_bn2        <<<dim3(COUT_, B_), 256, 0, stream>>>(out, stats + 1536, stats + 1792);
}